// Round 16
// baseline (139.723 us; speedup 1.0000x reference)
//
#include <hip/hip_runtime.h>
#include <math.h>

// Problem constants
#define BB 2
#define HH 64
#define WW 64
#define DM 128
#define EE 256
#define NN 16
#define RR 8
#define HW (HH*WW)          // 4096

__device__ __forceinline__ float gelu_exact(float v) {
    return 0.5f * v * (1.f + erff(v * 0.70710678118654752440f));
}
__device__ __forceinline__ float softplus_f(float v) {
    return fmaxf(v, 0.f) + log1pf(__expf(-fabsf(v)));
}

// DPP row_shr within 16-lane rows, old=0 (invalid lanes read 0 under either
// bound_ctrl convention; 0 = additive identity for the B-chain, A-chain is
// masked explicitly). Pure VALU.
template<int S>
__device__ __forceinline__ float dpp_shr0(float x) {
    return __int_as_float(__builtin_amdgcn_update_dpp(
        0, __float_as_int(x), 0x110 | S, 0xF, 0xF, false));
}
// DPP row_bcast15 (0x142) / row_bcast31 (0x143) with row-mask, old=0.
template<int CTRL, int RM>
__device__ __forceinline__ float dpp_bc0(float x) {
    return __int_as_float(__builtin_amdgcn_update_dpp(
        0, __float_as_int(x), CTRL, RM, 0xF, false));
}

// ---------------------------------------------------------------------------
// K1a: u = gelu(x@ipw^T + ipb) -> u_t[B,E,H,W]. grid = 128 rows x 8 e-chunks.
// (R12 version.)
// ---------------------------------------------------------------------------
__global__ __launch_bounds__(256) void k1a_u(
    const float* __restrict__ x,
    const float* __restrict__ ipw, const float* __restrict__ ipb,
    float* __restrict__ u_t)
{
    __shared__ float xs[64][129];

    const int blk = blockIdx.x;
    const int row = blk >> 3;            // b*64 + i
    const int ec  = blk & 7;
    const int b = row >> 6, i = row & 63;
    const int t = threadIdx.x;
    const int w = __builtin_amdgcn_readfirstlane(t >> 6);
    const int j = t & 63;

    const float* xrow = x + (size_t)row * (WW * DM);
    for (int idx = t; idx < WW * DM; idx += 256)
        xs[idx >> 7][idx & 127] = xrow[idx];
    __syncthreads();

    const int e0 = ec * 32 + w * 8;
    float acc[8];
    #pragma unroll
    for (int ee = 0; ee < 8; ++ee) acc[ee] = 0.f;

    for (int k = 0; k < DM; ++k) {
        const float xv = xs[j][k];
        #pragma unroll
        for (int ee = 0; ee < 8; ++ee)
            acc[ee] = fmaf(xv, ipw[(e0 + ee) * DM + k], acc[ee]);
    }
    #pragma unroll
    for (int ee = 0; ee < 8; ++ee) {
        const int e = e0 + ee;
        u_t[(((size_t)(b * EE + e) * HH + i) << 6) + j] = gelu_exact(acc[ee] + ipb[e]);
    }
}

// ---------------------------------------------------------------------------
// K1b1: dbc = u@xpw^T (+bias). 1024 blocks, 4 waves, K-split + LDS reduce.
// ---------------------------------------------------------------------------
__global__ __launch_bounds__(256) void k1b1_dbc(
    const float* __restrict__ u_t,
    const float* __restrict__ xpw, const float* __restrict__ xpb,
    float* __restrict__ dbc_g, float* __restrict__ Bm_t, float* __restrict__ Cm_t)
{
    __shared__ float xw[6][260];
    __shared__ float part[4][6][68];

    const int blk = blockIdx.x;
    const int cg = blk & 7;
    const int row = blk >> 3;            // b*64 + i
    const int b = row >> 6, i = row & 63;
    const int c0 = 6 * cg;
    const int t = threadIdx.x;
    const int w2 = __builtin_amdgcn_readfirstlane(t >> 6);
    const int j = t & 63;

    for (int idx = t; idx < 6 * 64; idx += 256) {
        const int cc = idx >> 6, e4 = idx & 63;
        *(float4*)&xw[cc][4 * e4] = ((const float4*)xpw)[(size_t)(c0 + cc) * 64 + e4];
    }
    __syncthreads();

    const float* ub = u_t + (((size_t)(b * EE)) << 12) + (i << 6) + j;
    const int ebase = 64 * w2;

    float acc[6] = {0.f, 0.f, 0.f, 0.f, 0.f, 0.f};
    for (int e4 = 0; e4 < 16; ++e4) {
        const int e = ebase + 4 * e4;
        const float u0 = ub[(size_t)(e + 0) << 12];
        const float u1 = ub[(size_t)(e + 1) << 12];
        const float u2 = ub[(size_t)(e + 2) << 12];
        const float u3 = ub[(size_t)(e + 3) << 12];
        #pragma unroll
        for (int cc = 0; cc < 6; ++cc) {
            const float4 wv = *(const float4*)&xw[cc][e];
            acc[cc] = fmaf(u0, wv.x, acc[cc]);
            acc[cc] = fmaf(u1, wv.y, acc[cc]);
            acc[cc] = fmaf(u2, wv.z, acc[cc]);
            acc[cc] = fmaf(u3, wv.w, acc[cc]);
        }
    }
    #pragma unroll
    for (int cc = 0; cc < 6; ++cc) part[w2][cc][j] = acc[cc];
    __syncthreads();

    for (int idx = t; idx < 6 * 64; idx += 256) {
        const int cc = idx >> 6, j2 = idx & 63;
        const int c = c0 + cc;
        const float s = ((part[0][cc][j2] + part[1][cc][j2]) +
                         (part[2][cc][j2] + part[3][cc][j2])) + xpb[c];
        if (c < 16) {
            dbc_g[((size_t)row * 16 + c) * 64 + j2] = s;
        } else if (c < 32) {
            const int n = c - 16;
            Bm_t[(((size_t)(b * NN + n) * HH + i) << 6) + j2] = s;
        } else {
            const int n = c - 32;
            Cm_t[(((size_t)(b * NN + n) * HH + i) << 6) + j2] = s;
        }
    }
}

// ---------------------------------------------------------------------------
// K1b2: deltaT/L = softplus(d@dtw^T + b). 512 blocks. e scalar -> s_loads.
// ---------------------------------------------------------------------------
__global__ __launch_bounds__(256) void k1b2_delta(
    const float* __restrict__ dbc_g,
    const float* __restrict__ dtTw, const float* __restrict__ dtTb,
    const float* __restrict__ dtLw, const float* __restrict__ dtLb,
    float* __restrict__ dT_t, float* __restrict__ dL_t)
{
    __shared__ float db[16][68];

    const int blk = blockIdx.x;
    const int eq = blk & 3;
    const int row = blk >> 2;            // b*64 + i
    const int b = row >> 6, i = row & 63;
    const int t = threadIdx.x;
    const int w2 = __builtin_amdgcn_readfirstlane(t >> 6);
    const int j = t & 63;

    for (int idx = t; idx < 16 * 64; idx += 256) {
        const int c = idx >> 6, j2 = idx & 63;
        db[c][j2] = dbc_g[((size_t)row * 16 + c) * 64 + j2];
    }
    __syncthreads();

    float dtv[8], dlv[8];
    #pragma unroll
    for (int r = 0; r < 8; ++r) { dtv[r] = db[r][j]; dlv[r] = db[8 + r][j]; }

    #pragma unroll 4
    for (int k = 0; k < 16; ++k) {
        const int e = 64 * eq + w2 + 4 * k;
        float sT = dtTb[e], sL = dtLb[e];
        #pragma unroll
        for (int r = 0; r < 8; ++r) {
            sT = fmaf(dtv[r], dtTw[e * RR + r], sT);
            sL = fmaf(dlv[r], dtLw[e * RR + r], sL);
        }
        dT_t[(((size_t)(b * EE + e) * HH + i) << 6) + j] = softplus_f(sT);
        dL_t[(((size_t)(b * EE + e) * HH + i) << 6) + j] = softplus_f(sL);
    }
}

// ---------------------------------------------------------------------------
// K2a (REWRITTEN): one WAVE per channel (b,e,n). Block = (b,e): 1024 thr
// = 16 waves; wave n owns channel n; lane = column. 8192 waves total =
// 8 waves/SIMD (4x the old occupancy) — latency hidden by TLP.
// Per row: 64-lane pair-scan fully in DPP VALU: 4x row_shr{1,2,4,8}
// (16-lane segments) + row_bcast15(rows 1,3) + row_bcast31(rows 2,3)
// seams. h = inclusive B directly. Channel reduce via parts[16][8][64]
// LDS (lane-contiguous, conflict-free), finalize every 8 rows.
// dT/dL/u double-buffer-staged through LDS (issue-early/write-late).
// __launch_bounds__(1024,8): VGPR<=64 -> 2 blocks/CU = 32 waves/CU.
// ---------------------------------------------------------------------------
__global__ __launch_bounds__(1024, 8) void k2a_scan(
    const float* __restrict__ u_t, const float* __restrict__ dT_t,
    const float* __restrict__ dL_t, const float* __restrict__ Bm_t,
    const float* __restrict__ Cm_t, const float* __restrict__ ATl,
    const float* __restrict__ ALl, const float* __restrict__ Dp,
    float* __restrict__ ys_t)
{
    __shared__ float sdT[2][8][64];       // 4KB
    __shared__ float sdL[2][8][64];       // 4KB
    __shared__ float su [2][8][64];       // 4KB
    __shared__ float parts[NN][8][64];    // 32KB  (total 44KB -> 2 blocks/CU)

    const int be = blockIdx.x;            // b*256 + e
    const int b = be >> 8, e = be & 255;
    const int t = threadIdx.x;
    const int n = __builtin_amdgcn_readfirstlane(t >> 6);  // wave = channel
    const int lane = t & 63;
    const int jj = lane & 15;
    const int rq = lane >> 4;

    const float LOG2E = 1.44269504088896340736f;
    const float AT2 = -__expf(ATl[e * NN + n]) * LOG2E;
    const float AL2 = -__expf(ALl[e * NN + n]) * LOG2E;
    const float De = Dp[e];

    const float* dTg = dT_t + ((size_t)be << 12);
    const float* dLg = dL_t + ((size_t)be << 12);
    const float* ug  = u_t  + ((size_t)be << 12);
    const float* bmp = Bm_t + ((size_t)(b * NN + n) << 12) + lane;
    const float* cmp = Cm_t + ((size_t)(b * NN + n) << 12) + lane;
    float* ysf = ys_t + ((size_t)be << 12);

    // prolog: stage chunk 0 (flat 1536 floats = dT|dL|u rows 0..7)
    #pragma unroll
    for (int q = 0; q < 2; ++q) {
        const int idx = t + (q << 10);
        if (idx < 1536) {
            const int a = idx >> 9, o = idx & 511;
            const float* src = (a == 0) ? dTg : (a == 1) ? dLg : ug;
            const float v = src[o];
            float* dst = (a == 0) ? &sdT[0][0][0]
                       : (a == 1) ? &sdL[0][0][0] : &su[0][0][0];
            dst[o] = v;
        }
    }
    __syncthreads();

    float h = 0.f;

    for (int ch = 0; ch < 8; ++ch) {
        const int buf = ch & 1;

        // issue next chunk's global loads early (fenced against sinking)
        float nv0 = 0.f, nv1 = 0.f;
        if (ch < 7) {
            { const int a = t >> 9, o = t & 511;
              const float* src = (a == 0) ? dTg : dLg;
              nv0 = src[((ch + 1) << 9) + o]; }
            if (t < 512) nv1 = ug[((ch + 1) << 9) + t];
            __builtin_amdgcn_sched_barrier(0);
        }

        #pragma unroll 2
        for (int r = 0; r < 8; ++r) {
            const int i = (ch << 3) + r;
            const float dT = sdT[buf][r][lane];
            const float dL = sdL[buf][r][lane];
            const float uu = su[buf][r][lane];
            const float bm = bmp[i << 6];
            const float cm = cmp[i << 6];

            const float aT = exp2f(dT * AT2);
            float A = exp2f(dL * AL2);
            float B = fmaf(aT, h, (dT + dL) * bm * uu);

            // 16-lane segment scan (DPP row_shr)
            { const float uA = dpp_shr0<1>(A), uB = dpp_shr0<1>(B);
              B = fmaf(A, uB, B); A *= (jj >= 1) ? uA : 1.f; }
            { const float uA = dpp_shr0<2>(A), uB = dpp_shr0<2>(B);
              B = fmaf(A, uB, B); A *= (jj >= 2) ? uA : 1.f; }
            { const float uA = dpp_shr0<4>(A), uB = dpp_shr0<4>(B);
              B = fmaf(A, uB, B); A *= (jj >= 4) ? uA : 1.f; }
            { const float uA = dpp_shr0<8>(A), uB = dpp_shr0<8>(B);
              B = fmaf(A, uB, B); A *= (jj >= 8) ? uA : 1.f; }
            // seam 1: row_bcast15 -> rows 1,3 combine with previous row agg
            { const float uA = dpp_bc0<0x142, 0xA>(A), uB = dpp_bc0<0x142, 0xA>(B);
              B = fmaf(A, uB, B); A *= (rq & 1) ? uA : 1.f; }
            // seam 2: row_bcast31 -> rows 2,3 combine with rows0+1 agg
            { const float uB = dpp_bc0<0x143, 0xC>(B);
              B = fmaf(A, uB, B); }

            h = B;
            parts[n][r][lane] = h * cm;
        }

        // write next chunk into the other stage buffer (latency covered)
        if (ch < 7) {
            { const int a = t >> 9, o = t & 511;
              float* dst = (a == 0) ? &sdT[buf ^ 1][0][0] : &sdL[buf ^ 1][0][0];
              dst[o] = nv0; }
            if (t < 512) (&su[buf ^ 1][0][0])[t] = nv1;
        }
        __syncthreads();

        // finalize 8 rows: threads 0..511, one output each
        if (t < 512) {
            const int frow = t >> 6, fcol = t & 63;
            float s = 0.f;
            #pragma unroll
            for (int c2 = 0; c2 < NN; ++c2) s += parts[c2][frow][fcol];
            const float uuf = su[buf][frow][fcol];
            ysf[(((ch << 3) + frow) << 6) + fcol] = gelu_exact(fmaf(uuf, De, s));
        }
        __syncthreads();
    }
}

// ---------------------------------------------------------------------------
// K3: out projection. grid = 128 rows x 4 d-chunks. (R12 version.)
// ---------------------------------------------------------------------------
__global__ __launch_bounds__(256) void k3_outproj(
    const float* __restrict__ ys_t,
    const float* __restrict__ ow, const float* __restrict__ ob,
    float* __restrict__ out)
{
    __shared__ float ysL[64][65];

    const int blk = blockIdx.x;
    const int row = blk >> 2;
    const int dc  = blk & 3;
    const int b = row >> 6, i = row & 63;
    const int t = threadIdx.x;
    const int w = __builtin_amdgcn_readfirstlane(t >> 6);
    const int j = t & 63;
    const int d0 = dc * 32 + w * 8;

    float acc[8];
    #pragma unroll
    for (int dd = 0; dd < 8; ++dd) acc[dd] = 0.f;

    for (int ch = 0; ch < 4; ++ch) {
        __syncthreads();
        for (int idx = t; idx < 64 * 64; idx += 256) {
            const int ee = idx >> 6, jj = idx & 63;
            ysL[ee][jj] = ys_t[(((size_t)(b * EE + ch * 64 + ee) * HH + i) << 6) + jj];
        }
        __syncthreads();
        for (int e64 = 0; e64 < 64; ++e64) {
            const float yv = ysL[e64][j];
            const int e = ch * 64 + e64;
            #pragma unroll
            for (int dd = 0; dd < 8; ++dd)
                acc[dd] = fmaf(ow[(d0 + dd) * EE + e], yv, acc[dd]);
        }
    }

    float* orow = out + (size_t)row * (WW * DM) + (size_t)j * DM + d0;
    #pragma unroll
    for (int dd = 0; dd < 8; ++dd) orow[dd] = acc[dd] + ob[d0 + dd];
}

extern "C" void kernel_launch(void* const* d_in, const int* in_sizes, int n_in,
                              void* d_out, int out_size, void* d_ws, size_t ws_size,
                              hipStream_t stream) {
    const float* x    = (const float*)d_in[0];
    const float* ipw  = (const float*)d_in[1];
    const float* ipb  = (const float*)d_in[2];
    const float* xpw  = (const float*)d_in[3];
    const float* xpb  = (const float*)d_in[4];
    const float* dtTw = (const float*)d_in[5];
    const float* dtTb = (const float*)d_in[6];
    const float* dtLw = (const float*)d_in[7];
    const float* dtLb = (const float*)d_in[8];
    const float* ATl  = (const float*)d_in[9];
    const float* ALl  = (const float*)d_in[10];
    const float* Dp   = (const float*)d_in[11];
    const float* ow   = (const float*)d_in[12];
    const float* ob   = (const float*)d_in[13];
    float* out = (float*)d_out;

    float* ws    = (float*)d_ws;
    float* u_t   = ws;
    float* dT_t  = u_t  + (size_t)BB * EE * HW;
    float* dL_t  = dT_t + (size_t)BB * EE * HW;
    float* ys_t  = dL_t + (size_t)BB * EE * HW;
    float* Bm_t  = ys_t + (size_t)BB * EE * HW;
    float* Cm_t  = Bm_t + (size_t)BB * NN * HW;
    float* dbc_g = Cm_t + (size_t)BB * NN * HW;   // [128][16][64]

    k1a_u<<<BB * HH * 8, 256, 0, stream>>>(x, ipw, ipb, u_t);
    k1b1_dbc<<<BB * HH * 8, 256, 0, stream>>>(u_t, xpw, xpb, dbc_g, Bm_t, Cm_t);
    k1b2_delta<<<BB * HH * 4, 256, 0, stream>>>(dbc_g, dtTw, dtTb, dtLw, dtLb,
                                                dT_t, dL_t);
    k2a_scan<<<BB * EE, 1024, 0, stream>>>(u_t, dT_t, dL_t, Bm_t, Cm_t,
                                           ATl, ALl, Dp, ys_t);
    k3_outproj<<<BB * HH * 4, 256, 0, stream>>>(ys_t, ow, ob, out);
}

// Round 17
// 103.977 us; speedup vs baseline: 1.3438x; 1.3438x over previous
//
#include <hip/hip_runtime.h>
#include <math.h>

// Problem constants
#define BB 2
#define HH 64
#define WW 64
#define DM 128
#define EE 256
#define NN 16
#define RR 8
#define HW (HH*WW)          // 4096
#define CH 16               // k2a rows per pipeline chunk
#define NCH (HH/CH)         // 4 chunks

typedef __attribute__((ext_vector_type(8))) short bf16x8;
typedef __attribute__((ext_vector_type(4))) float f32x4;

__device__ __forceinline__ float gelu_exact(float v) {
    return 0.5f * v * (1.f + erff(v * 0.70710678118654752440f));
}
__device__ __forceinline__ float softplus_f(float v) {
    return fmaxf(v, 0.f) + log1pf(__expf(-fabsf(v)));
}

// float -> bf16 bits, round-to-nearest-even
__device__ __forceinline__ short f2bf(float f) {
    unsigned u = __float_as_uint(f);
    u += 0x7FFFu + ((u >> 16) & 1u);
    return (short)(u >> 16);
}
__device__ __forceinline__ bf16x8 cvt8(const float* p) {
    const float4 v0 = *(const float4*)p;
    const float4 v1 = *(const float4*)(p + 4);
    bf16x8 r;
    r[0] = f2bf(v0.x); r[1] = f2bf(v0.y); r[2] = f2bf(v0.z); r[3] = f2bf(v0.w);
    r[4] = f2bf(v1.x); r[5] = f2bf(v1.y); r[6] = f2bf(v1.z); r[7] = f2bf(v1.w);
    return r;
}

template<int S>
__device__ __forceinline__ float dpp_shr0(float x) {
    return __int_as_float(__builtin_amdgcn_update_dpp(
        0, __float_as_int(x), 0x110 | S, 0xF, 0xF, false));
}

// ---------------------------------------------------------------------------
// K1a (MFMA): u = gelu(x@ipw^T + ipb) -> u_t[B,E,H,W].
// grid = 128 rows x 4 e-quarters = 512 blocks, 256 thr = 4 waves.
// Wave w = j-tile (j0=16w); block covers 4 e-tiles (64 e's).
// A = ipw[e,k] (lane: row=l&15, k=(l>>4)*8+i, contiguous), B = x[j,k]
// (lane: col=l&15, k contiguous). D: row(e)=(l>>4)*4+r, col(j)=l&15.
// No LDS, no barriers; x/ipw L2-resident.
// ---------------------------------------------------------------------------
__global__ __launch_bounds__(256) void k1a_u(
    const float* __restrict__ x,
    const float* __restrict__ ipw, const float* __restrict__ ipb,
    float* __restrict__ u_t)
{
    const int blk = blockIdx.x;          // (b*64+i)*4 + eq
    const int eq = blk & 3;
    const int row = blk >> 2;            // b*64 + i
    const int b = row >> 6, i = row & 63;
    const int t = threadIdx.x;
    const int w = t >> 6;
    const int lane = t & 63;
    const int l16 = lane & 15, lq = lane >> 4;
    const int j0 = 16 * w;
    const int e_base = 64 * eq;

    f32x4 acc0 = {0.f, 0.f, 0.f, 0.f};
    f32x4 acc1 = {0.f, 0.f, 0.f, 0.f};
    f32x4 acc2 = {0.f, 0.f, 0.f, 0.f};
    f32x4 acc3 = {0.f, 0.f, 0.f, 0.f};

    const float* xrow = x + (size_t)row * (WW * DM);

    #pragma unroll
    for (int ks = 0; ks < 4; ++ks) {
        const int k0 = ks * 32 + lq * 8;
        const bf16x8 bfrag = cvt8(xrow + (size_t)(j0 + l16) * DM + k0);

        const bf16x8 a0 = cvt8(ipw + (size_t)(e_base +  0 + l16) * DM + k0);
        acc0 = __builtin_amdgcn_mfma_f32_16x16x32_bf16(a0, bfrag, acc0, 0, 0, 0);
        const bf16x8 a1 = cvt8(ipw + (size_t)(e_base + 16 + l16) * DM + k0);
        acc1 = __builtin_amdgcn_mfma_f32_16x16x32_bf16(a1, bfrag, acc1, 0, 0, 0);
        const bf16x8 a2 = cvt8(ipw + (size_t)(e_base + 32 + l16) * DM + k0);
        acc2 = __builtin_amdgcn_mfma_f32_16x16x32_bf16(a2, bfrag, acc2, 0, 0, 0);
        const bf16x8 a3 = cvt8(ipw + (size_t)(e_base + 48 + l16) * DM + k0);
        acc3 = __builtin_amdgcn_mfma_f32_16x16x32_bf16(a3, bfrag, acc3, 0, 0, 0);
    }

    #pragma unroll
    for (int r = 0; r < 4; ++r) {
        const int em = lq * 4 + r;
        const int j = j0 + l16;
        {
            const int e = e_base + em;
            u_t[(((size_t)(b * EE + e) * HH + i) << 6) + j] =
                gelu_exact(acc0[r] + ipb[e]);
        }
        {
            const int e = e_base + 16 + em;
            u_t[(((size_t)(b * EE + e) * HH + i) << 6) + j] =
                gelu_exact(acc1[r] + ipb[e]);
        }
        {
            const int e = e_base + 32 + em;
            u_t[(((size_t)(b * EE + e) * HH + i) << 6) + j] =
                gelu_exact(acc2[r] + ipb[e]);
        }
        {
            const int e = e_base + 48 + em;
            u_t[(((size_t)(b * EE + e) * HH + i) << 6) + j] =
                gelu_exact(acc3[r] + ipb[e]);
        }
    }
}

// ---------------------------------------------------------------------------
// K1b1: dbc = u@xpw^T (+bias). 1024 blocks, 4 waves, K-split + LDS reduce.
// (R12 version, unchanged.)
// ---------------------------------------------------------------------------
__global__ __launch_bounds__(256) void k1b1_dbc(
    const float* __restrict__ u_t,
    const float* __restrict__ xpw, const float* __restrict__ xpb,
    float* __restrict__ dbc_g, float* __restrict__ Bm_t, float* __restrict__ Cm_t)
{
    __shared__ float xw[6][260];
    __shared__ float part[4][6][68];

    const int blk = blockIdx.x;
    const int cg = blk & 7;
    const int row = blk >> 3;            // b*64 + i
    const int b = row >> 6, i = row & 63;
    const int c0 = 6 * cg;
    const int t = threadIdx.x;
    const int w2 = __builtin_amdgcn_readfirstlane(t >> 6);
    const int j = t & 63;

    for (int idx = t; idx < 6 * 64; idx += 256) {
        const int cc = idx >> 6, e4 = idx & 63;
        *(float4*)&xw[cc][4 * e4] = ((const float4*)xpw)[(size_t)(c0 + cc) * 64 + e4];
    }
    __syncthreads();

    const float* ub = u_t + (((size_t)(b * EE)) << 12) + (i << 6) + j;
    const int ebase = 64 * w2;

    float acc[6] = {0.f, 0.f, 0.f, 0.f, 0.f, 0.f};
    for (int e4 = 0; e4 < 16; ++e4) {
        const int e = ebase + 4 * e4;
        const float u0 = ub[(size_t)(e + 0) << 12];
        const float u1 = ub[(size_t)(e + 1) << 12];
        const float u2 = ub[(size_t)(e + 2) << 12];
        const float u3 = ub[(size_t)(e + 3) << 12];
        #pragma unroll
        for (int cc = 0; cc < 6; ++cc) {
            const float4 wv = *(const float4*)&xw[cc][e];
            acc[cc] = fmaf(u0, wv.x, acc[cc]);
            acc[cc] = fmaf(u1, wv.y, acc[cc]);
            acc[cc] = fmaf(u2, wv.z, acc[cc]);
            acc[cc] = fmaf(u3, wv.w, acc[cc]);
        }
    }
    #pragma unroll
    for (int cc = 0; cc < 6; ++cc) part[w2][cc][j] = acc[cc];
    __syncthreads();

    for (int idx = t; idx < 6 * 64; idx += 256) {
        const int cc = idx >> 6, j2 = idx & 63;
        const int c = c0 + cc;
        const float s = ((part[0][cc][j2] + part[1][cc][j2]) +
                         (part[2][cc][j2] + part[3][cc][j2])) + xpb[c];
        if (c < 16) {
            dbc_g[((size_t)row * 16 + c) * 64 + j2] = s;
        } else if (c < 32) {
            const int n = c - 16;
            Bm_t[(((size_t)(b * NN + n) * HH + i) << 6) + j2] = s;
        } else {
            const int n = c - 32;
            Cm_t[(((size_t)(b * NN + n) * HH + i) << 6) + j2] = s;
        }
    }
}

// ---------------------------------------------------------------------------
// K1b2: deltaT/L = softplus(d@dtw^T + b). 512 blocks. (R12 version.)
// ---------------------------------------------------------------------------
__global__ __launch_bounds__(256) void k1b2_delta(
    const float* __restrict__ dbc_g,
    const float* __restrict__ dtTw, const float* __restrict__ dtTb,
    const float* __restrict__ dtLw, const float* __restrict__ dtLb,
    float* __restrict__ dT_t, float* __restrict__ dL_t)
{
    __shared__ float db[16][68];

    const int blk = blockIdx.x;
    const int eq = blk & 3;
    const int row = blk >> 2;            // b*64 + i
    const int b = row >> 6, i = row & 63;
    const int t = threadIdx.x;
    const int w2 = __builtin_amdgcn_readfirstlane(t >> 6);
    const int j = t & 63;

    for (int idx = t; idx < 16 * 64; idx += 256) {
        const int c = idx >> 6, j2 = idx & 63;
        db[c][j2] = dbc_g[((size_t)row * 16 + c) * 64 + j2];
    }
    __syncthreads();

    float dtv[8], dlv[8];
    #pragma unroll
    for (int r = 0; r < 8; ++r) { dtv[r] = db[r][j]; dlv[r] = db[8 + r][j]; }

    #pragma unroll 4
    for (int k = 0; k < 16; ++k) {
        const int e = 64 * eq + w2 + 4 * k;
        float sT = dtTb[e], sL = dtLb[e];
        #pragma unroll
        for (int r = 0; r < 8; ++r) {
            sT = fmaf(dtv[r], dtTw[e * RR + r], sT);
            sL = fmaf(dlv[r], dtLw[e * RR + r], sL);
        }
        dT_t[(((size_t)(b * EE + e) * HH + i) << 6) + j] = softplus_f(sT);
        dL_t[(((size_t)(b * EE + e) * HH + i) << 6) + j] = softplus_f(sL);
    }
}

// ---------------------------------------------------------------------------
// K2a: wavefront scan, LDS-pipelined (R12 version — best measured: 47.4us).
// ---------------------------------------------------------------------------
__device__ __forceinline__ float row_scan_raw(
    float4 dT4, float4 dL4, float4 u4, float4 bm4, float4 cm4,
    float AT2, float AL2, float* h, int c, int jj)
{
    const float dTv[4] = {dT4.x, dT4.y, dT4.z, dT4.w};
    const float dLv[4] = {dL4.x, dL4.y, dL4.z, dL4.w};
    const float uv[4]  = {u4.x,  u4.y,  u4.z,  u4.w};
    const float bmv[4] = {bm4.x, bm4.y, bm4.z, bm4.w};
    const float cmv[4] = {cm4.x, cm4.y, cm4.z, cm4.w};

    float cumA[4], cumB[4];
    {
        const float aT = exp2f(dTv[0] * AT2);
        cumA[0] = exp2f(dLv[0] * AL2);
        cumB[0] = fmaf(aT, h[0], (dTv[0] + dLv[0]) * bmv[0] * uv[0]);
    }
    #pragma unroll
    for (int k = 1; k < 4; ++k) {
        const float aT = exp2f(dTv[k] * AT2);
        const float aL = exp2f(dLv[k] * AL2);
        const float bk = fmaf(aT, h[k], (dTv[k] + dLv[k]) * bmv[k] * uv[k]);
        cumB[k] = fmaf(aL, cumB[k - 1], bk);
        cumA[k] = aL * cumA[k - 1];
    }

    float Ag = cumA[3], Bg = cumB[3];
    { const float uA = dpp_shr0<1>(Ag), uB = dpp_shr0<1>(Bg);
      Bg = fmaf(Ag, uB, Bg); Ag *= (jj >= 1) ? uA : 1.f; }
    { const float uA = dpp_shr0<2>(Ag), uB = dpp_shr0<2>(Bg);
      Bg = fmaf(Ag, uB, Bg); Ag *= (jj >= 2) ? uA : 1.f; }
    { const float uA = dpp_shr0<4>(Ag), uB = dpp_shr0<4>(Bg);
      Bg = fmaf(Ag, uB, Bg); Ag *= (jj >= 4) ? uA : 1.f; }
    { const float uB = dpp_shr0<8>(Bg);
      Bg = fmaf(Ag, uB, Bg); }
    const float pB = dpp_shr0<1>(Bg);

    float g[4];
    #pragma unroll
    for (int k = 0; k < 4; ++k) {
        h[k] = fmaf(cumA[k], pB, cumB[k]);
        g[k] = h[k] * cmv[k];
    }
    #pragma unroll
    for (int k = 0; k < 4; ++k) {
        g[k] += __shfl_xor(g[k], 16, 64);
        g[k] += __shfl_xor(g[k], 32, 64);
    }
    return (c == 0) ? g[0] : (c == 1) ? g[1] : (c == 2) ? g[2] : g[3];
}

__global__ __launch_bounds__(256, 2) void k2a_scan(
    const float* __restrict__ u_t, const float* __restrict__ dT_t,
    const float* __restrict__ dL_t, const float* __restrict__ Bm_t,
    const float* __restrict__ Cm_t, const float* __restrict__ ATl,
    const float* __restrict__ ALl, const float* __restrict__ Dp,
    float* __restrict__ ys_t)
{
    __shared__ float sdT[2][CH][64];
    __shared__ float sdL[2][CH][64];
    __shared__ float su [2][CH][64];
    __shared__ float parts[2][4][CH][64];

    const int be = blockIdx.x;           // b*256 + e
    const int b = be >> 8, e = be & 255;
    const int t = threadIdx.x;
    const int w = __builtin_amdgcn_readfirstlane(t >> 6);
    const int lane = t & 63;
    const int c = lane >> 4, jj = lane & 15;
    const int n = w * 4 + c;
    const int col = 4 * jj + c;

    const float LOG2E = 1.44269504088896340736f;
    const float AT2 = -__expf(ATl[e * NN + n]) * LOG2E;
    const float AL2 = -__expf(ALl[e * NN + n]) * LOG2E;
    const float De = Dp[e];

    const float* dTg = dT_t + ((size_t)be << 12);
    const float* dLg = dL_t + ((size_t)be << 12);
    const float* ug  = u_t  + ((size_t)be << 12);
    const float* bmp = Bm_t + ((size_t)(b * NN + n) << 12) + 4 * jj;
    const float* cmp = Cm_t + ((size_t)(b * NN + n) << 12) + 4 * jj;

    const int srow = t >> 4;
    const int scol = (t & 15) << 2;

    const int fcol = t & 63;
    const float* uf = ug + fcol;
    float* ysf = ys_t + ((size_t)be << 12) + fcol;

    float4 ldT, ldL, lu;
    {
        const size_t off = ((size_t)srow << 6) + scol;
        ldT = *(const float4*)(dTg + off);
        ldL = *(const float4*)(dLg + off);
        lu  = *(const float4*)(ug  + off);
        *(float4*)&sdT[0][srow][scol] = ldT;
        *(float4*)&sdL[0][srow][scol] = ldL;
        *(float4*)&su [0][srow][scol] = lu;
    }
    __syncthreads();

    float4 bm4 = *(const float4*)(bmp);
    float4 cm4 = *(const float4*)(cmp);

    float h[4] = {0.f, 0.f, 0.f, 0.f};

    for (int ch = 0; ch < NCH; ++ch) {
        const int buf = ch & 1;

        if (ch + 1 < NCH) {
            const size_t off = ((size_t)((ch + 1) * CH + srow) << 6) + scol;
            ldT = *(const float4*)(dTg + off);
            ldL = *(const float4*)(dLg + off);
            lu  = *(const float4*)(ug  + off);
            __builtin_amdgcn_sched_barrier(0);
        }

        #pragma unroll
        for (int r = 0; r < CH; ++r) {
            const int i = ch * CH + r;
            const int ipn = (i + 1 < HH) ? i + 1 : i;
            const float4 bm4n = *(const float4*)(bmp + (ipn << 6));
            const float4 cm4n = *(const float4*)(cmp + (ipn << 6));

            const float4 dT4 = *(const float4*)&sdT[buf][r][4 * jj];
            const float4 dL4 = *(const float4*)&sdL[buf][r][4 * jj];
            const float4 u4  = *(const float4*)&su [buf][r][4 * jj];

            parts[buf][w][r][col] =
                row_scan_raw(dT4, dL4, u4, bm4, cm4, AT2, AL2, h, c, jj);

            bm4 = bm4n; cm4 = cm4n;
        }

        if (ch + 1 < NCH) {
            *(float4*)&sdT[buf ^ 1][srow][scol] = ldT;
            *(float4*)&sdL[buf ^ 1][srow][scol] = ldL;
            *(float4*)&su [buf ^ 1][srow][scol] = lu;
        }
        __syncthreads();

        #pragma unroll
        for (int q = 0; q < 4; ++q) {
            const int r = (t >> 6) * 4 + q;
            const int i = ch * CH + r;
            const float s = ((parts[buf][0][r][fcol] + parts[buf][1][r][fcol]) +
                             (parts[buf][2][r][fcol] + parts[buf][3][r][fcol]));
            ysf[i << 6] = gelu_exact(fmaf(uf[i << 6], De, s));
        }
    }
}

// ---------------------------------------------------------------------------
// K3 (MFMA): out = ys@ow^T + ob. grid = 128 rows x 4 j-quarters = 512 blocks.
// Stage ysT[16j][264e] bf16 in LDS (coalesced reads, one barrier).
// A = ysT (lane: row(j)=l&15, k(e) contiguous -> ds_read_b128),
// B = ow[d,e] (lane: col(d)=l&15, k(e)=(l>>4)*8+i contiguous from global).
// D: row(j)=(l>>4)*4+r, col(d)=l&15 -> coalesced out stores.
// Wave w handles d-tiles 2w, 2w+1.
// ---------------------------------------------------------------------------
__global__ __launch_bounds__(256) void k3_outproj(
    const float* __restrict__ ys_t,
    const float* __restrict__ ow, const float* __restrict__ ob,
    float* __restrict__ out)
{
    __shared__ short ysT[16][264];   // bf16 bits, padded (16B-aligned rows)

    const int blk = blockIdx.x;      // (b*64+i)*4 + jq
    const int jq = blk & 3;
    const int row = blk >> 2;
    const int b = row >> 6, i = row & 63;
    const int t = threadIdx.x;
    const int w = t >> 6;
    const int lane = t & 63;
    const int l16 = lane & 15, lq = lane >> 4;
    const int j0 = 16 * jq;

    // stage: ysT[jj][e] = bf16(ys_t[b,e,i,j0+jj]); reads coalesced (16 j's/e)
    for (int idx = t; idx < EE * 16; idx += 256) {
        const int e = idx >> 4, jj = idx & 15;
        ysT[jj][e] = f2bf(ys_t[(((size_t)(b * EE + e) * HH + i) << 6) + j0 + jj]);
    }
    __syncthreads();

    f32x4 acc0 = {0.f, 0.f, 0.f, 0.f};
    f32x4 acc1 = {0.f, 0.f, 0.f, 0.f};

    const int d0 = 32 * w;

    #pragma unroll
    for (int ks = 0; ks < 8; ++ks) {
        const int e0 = ks * 32 + lq * 8;
        const bf16x8 afrag = *(const bf16x8*)&ysT[l16][e0];

        const bf16x8 b0 = cvt8(ow + (size_t)(d0 + l16) * EE + e0);
        acc0 = __builtin_amdgcn_mfma_f32_16x16x32_bf16(afrag, b0, acc0, 0, 0, 0);
        const bf16x8 b1 = cvt8(ow + (size_t)(d0 + 16 + l16) * EE + e0);
        acc1 = __builtin_amdgcn_mfma_f32_16x16x32_bf16(afrag, b1, acc1, 0, 0, 0);
    }

    float* orow = out + (size_t)row * (WW * DM);
    #pragma unroll
    for (int r = 0; r < 4; ++r) {
        const int j = j0 + lq * 4 + r;
        orow[(size_t)j * DM + d0 + l16]      = acc0[r] + ob[d0 + l16];
        orow[(size_t)j * DM + d0 + 16 + l16] = acc1[r] + ob[d0 + 16 + l16];
    }
}

extern "C" void kernel_launch(void* const* d_in, const int* in_sizes, int n_in,
                              void* d_out, int out_size, void* d_ws, size_t ws_size,
                              hipStream_t stream) {
    const float* x    = (const float*)d_in[0];
    const float* ipw  = (const float*)d_in[1];
    const float* ipb  = (const float*)d_in[2];
    const float* xpw  = (const float*)d_in[3];
    const float* xpb  = (const float*)d_in[4];
    const float* dtTw = (const float*)d_in[5];
    const float* dtTb = (const float*)d_in[6];
    const float* dtLw = (const float*)d_in[7];
    const float* dtLb = (const float*)d_in[8];
    const float* ATl  = (const float*)d_in[9];
    const float* ALl  = (const float*)d_in[10];
    const float* Dp   = (const float*)d_in[11];
    const float* ow   = (const float*)d_in[12];
    const float* ob   = (const float*)d_in[13];
    float* out = (float*)d_out;

    float* ws    = (float*)d_ws;
    float* u_t   = ws;
    float* dT_t  = u_t  + (size_t)BB * EE * HW;
    float* dL_t  = dT_t + (size_t)BB * EE * HW;
    float* ys_t  = dL_t + (size_t)BB * EE * HW;
    float* Bm_t  = ys_t + (size_t)BB * EE * HW;
    float* Cm_t  = Bm_t + (size_t)BB * NN * HW;
    float* dbc_g = Cm_t + (size_t)BB * NN * HW;   // [128][16][64]

    k1a_u<<<BB * HH * 4, 256, 0, stream>>>(x, ipw, ipb, u_t);
    k1b1_dbc<<<BB * HH * 8, 256, 0, stream>>>(u_t, xpw, xpb, dbc_g, Bm_t, Cm_t);
    k1b2_delta<<<BB * HH * 4, 256, 0, stream>>>(dbc_g, dtTw, dtTb, dtLw, dtLb,
                                                dT_t, dL_t);
    k2a_scan<<<BB * EE, 256, 0, stream>>>(u_t, dT_t, dL_t, Bm_t, Cm_t,
                                          ATl, ALl, Dp, ys_t);
    k3_outproj<<<BB * HH * 4, 256, 0, stream>>>(ys_t, ow, ob, out);
}